// Round 4
// baseline (621.383 us; speedup 1.0000x reference)
//
#include <hip/hip_runtime.h>

// NeuralSpectralBlock1d on MI355X (gfx950)
// B=32, C=256, H=4096, PATCH=4, HEAD=8, DH=32, NT=4, NB=12
// v4 = v3 + (a) conflict-free c-major staging, (b) balanced wave<->tile remap
//      (4 enc + 2 dec tiles per wave; wave w <-> head w), (c) b128-quad attn1.
//      (resubmission: previous round failed in infra before any measurement)
//
//   wconv_kernel: enc_w(512x256) ++ dec_w(256x256) -> bf16 Wb in d_ws,
//                 MFMA fragment order: elem = ((m16*8+kt)*64 + quad*16+fm)*8 + j
//   nsb_kernel:   grid 2048 = 32 b * 64 col-chunks; block 512 thr (8 waves)
//     stage:   c-major: lane=h, 4 consecutive channels/thread/round ->
//              ds_write_b64 at lane*536 (16 bank starts x 4 = min; conflict-free),
//              global side = 4 scalar dword loads, each 256B coalesced.
//     phase 1: Y = Wb @ X barrier-free; wave owns enc tiles {4w..4w+3} and
//              dec tiles {32+2w, 33+2w}  -> E-write AND D-write both engage
//              all 8 waves (v3 had waves 6-7 idle in E, 0-4 idle in D).
//     phase 2: per half (32 cols): E-write -> attn1 (b128 swizzle-quad loads)
//              -> D-write + spectral -> attn2 + residual + store.
//
// LDS map (54784 B):
//   stage: Bl [0,34304)       64 h * 536 B (256 bf16 ch + pad)
//   E:  [0,33280)   32 cols * 260 words; (k,v) pair word, (d+4h)&31 swizzle,
//                   4-word pad/col for 16B-aligned b128 quad reads
//   D:  [0,16896)   32 cols * 528 B (overlay; E dead)
//   LT: [33280,50176) 8 patches * 4 l * 528 B
//   QL: [50176,54784) latent fp32 [h][l][36] (pad 36 -> aligned float4 reads)

typedef __attribute__((ext_vector_type(8))) short short8;
typedef __attribute__((ext_vector_type(4))) float f32x4;

#define BSTRIDE 536
#define ESTRIDE 260
#define DSTR    528
#define LTSTR   528
#define DOFF    0
#define LTOFF   33280
#define QLOFF   50176

__device__ __forceinline__ unsigned short f2bf(float f) {
  union { float f; unsigned int u; } c; c.f = f;
  unsigned int u = c.u + 0x7FFFu + ((c.u >> 16) & 1u);
  return (unsigned short)(u >> 16);
}
__device__ __forceinline__ float bf2f(unsigned short s) {
  union { unsigned int u; float f; } c; c.u = ((unsigned int)s) << 16;
  return c.f;
}
__device__ __forceinline__ unsigned int pack2bf(float lo, float hi) {
  return (unsigned int)f2bf(lo) | ((unsigned int)f2bf(hi) << 16);
}
__device__ __forceinline__ float lo_f(unsigned int u) {
  union { unsigned int x; float f; } c; c.x = u << 16; return c.f;
}
__device__ __forceinline__ float hi_f(unsigned int u) {
  union { unsigned int x; float f; } c; c.x = u & 0xffff0000u; return c.f;
}

// Wb fragment layout: element index = ((m16*8 + kt)*64 + quad*16 + fm)*8 + j
// source: W[row = m16*16 + fm][k = kt*32 + quad*8 + j]
__global__ void wconv_kernel(const float* __restrict__ enc_w,
                             const float* __restrict__ dec_w,
                             unsigned short* __restrict__ Wb) {
  const int g   = blockIdx.x * 256 + threadIdx.x;  // 96*256 = 24576 = 196608/8
  const int blk = g >> 6;        // m16*8 + kt
  const int lp  = g & 63;        // quad*16 + fm
  const int m16 = blk >> 3, kt = blk & 7;
  const int fm  = lp & 15, quad = lp >> 4;
  const int row = m16 * 16 + fm;
  const int k   = kt * 32 + quad * 8;
  const float* src = (row < 512) ? (enc_w + row * 256 + k)
                                 : (dec_w + (row - 512) * 256 + k);
  const float4 v0 = *(const float4*)(src);
  const float4 v1 = *(const float4*)(src + 4);
  ushort4 o0, o1;
  o0.x = f2bf(v0.x); o0.y = f2bf(v0.y); o0.z = f2bf(v0.z); o0.w = f2bf(v0.w);
  o1.x = f2bf(v1.x); o1.y = f2bf(v1.y); o1.z = f2bf(v1.z); o1.w = f2bf(v1.w);
  *(ushort4*)(Wb + g * 8)     = o0;
  *(ushort4*)(Wb + g * 8 + 4) = o1;
}

__global__ __launch_bounds__(512) void nsb_kernel(
    const float* __restrict__ x,
    const float* __restrict__ weights,
    const float* __restrict__ latent,
    const float* __restrict__ enc_b,
    const float* __restrict__ dec_b,
    const unsigned short* __restrict__ Wb,
    float* __restrict__ out)
{
  __shared__ __attribute__((aligned(16))) unsigned char smem[54784];
  const int t    = threadIdx.x;
  const int wv   = t >> 6;       // wave 0..7
  const int lane = t & 63;
  const int fm   = lane & 15;    // mfma m/n index
  const int quad = lane >> 4;    // mfma k-group / row-quad
  const int bb   = blockIdx.x >> 6;          // batch
  const int h0   = (blockIdx.x & 63) << 6;   // column base in H

  f32x4 acc[6][4];
#pragma unroll
  for (int i = 0; i < 6; ++i)
#pragma unroll
    for (int j = 0; j < 4; ++j)
      acc[i][j] = f32x4{0.f, 0.f, 0.f, 0.f};

  // ---- stage: c-major, conflict-free.  lane = h; 4 consecutive ch/round ----
  {
#pragma unroll
    for (int rd = 0; rd < 8; ++rd) {
      const int c0 = rd * 32 + wv * 4;
      const float* xp = x + (bb * 256 + c0) * 4096 + h0 + lane;
      const float a = xp[0];
      const float b = xp[4096];
      const float c = xp[8192];
      const float d = xp[12288];
      *(uint2*)(smem + lane * BSTRIDE + c0 * 2) =
          make_uint2(pack2bf(a, b), pack2bf(c, d));
    }
  }
  {
    const int e0 = t * 2;
    const float2 lv = *(const float2*)(latent + e0);
    int h_ = e0 >> 7, l_ = (e0 >> 5) & 3, d_ = e0 & 31;
    *(float*)(smem + QLOFF + (h_ * 144 + l_ * 36 + d_) * 4) = lv.x;
    const int e1 = e0 + 1;
    h_ = e1 >> 7; l_ = (e1 >> 5) & 3; d_ = e1 & 31;
    *(float*)(smem + QLOFF + (h_ * 144 + l_ * 36 + d_) * 4) = lv.y;
  }
  __syncthreads();

  // ---- phase 1: GEMM Y = W @ X, barrier-free; balanced tile map ----
  // wave tiles: i<4 -> enc tile (wv*4+i); i in {4,5} -> dec tile (32+2wv+i-4)
  {
    const unsigned char* Bb = smem + fm * BSTRIDE + quad * 16;
    const unsigned short* Ap = Wb + lane * 8;
#pragma unroll
    for (int kt = 0; kt < 8; ++kt) {
      short8 bfrag[4];
#pragma unroll
      for (int j = 0; j < 4; ++j) {
        const unsigned char* p = Bb + j * 16 * BSTRIDE + kt * 64;
        union { short8 s; uint2 u[2]; } tb;
        tb.u[0] = *(const uint2*)(p);
        tb.u[1] = *(const uint2*)(p + 8);
        bfrag[j] = tb.s;
      }
#pragma unroll
      for (int i = 0; i < 6; ++i) {
        const int ti = (i < 4) ? (wv * 4 + i) : (32 + wv * 2 + (i - 4));
        const short8 afrag = *(const short8*)(Ap + ti * 4096 + kt * 512);
#pragma unroll
        for (int j = 0; j < 4; ++j)
          acc[i][j] = __builtin_amdgcn_mfma_f32_16x16x32_bf16(afrag, bfrag[j], acc[i][j], 0, 0, 0);
      }
    }
  }
  __syncthreads();   // Bl dead after this; E overlays it

  // ---- epilogue setup: bias registers (balanced map) ----
  float biasr[6][4];
#pragma unroll
  for (int i = 0; i < 4; ++i)
#pragma unroll
    for (int r = 0; r < 4; ++r)
      biasr[i][r] = enc_b[wv * 64 + i * 16 + quad * 4 + r];
#pragma unroll
  for (int i = 4; i < 6; ++i)
#pragma unroll
    for (int r = 0; r < 4; ++r)
      biasr[i][r] = dec_b[wv * 32 + (i - 4) * 16 + quad * 4 + r];

#pragma unroll
  for (int hf = 0; hf < 2; ++hf) {
    // ---- E-write: all waves; wave w writes head h_=w only ----
#pragma unroll
    for (int i = 0; i < 4; ++i) {
#pragma unroll
      for (int jj = 0; jj < 2; ++jj) {
        const int col = jj * 16 + fm;  // 0..31 within half
#pragma unroll
        for (int r2 = 0; r2 < 2; ++r2) {
          const float v0 = acc[i][hf * 2 + jj][r2 * 2]     + biasr[i][r2 * 2];
          const float v1 = acc[i][hf * 2 + jj][r2 * 2 + 1] + biasr[i][r2 * 2 + 1];
          const int d_ = i * 8 + quad * 2 + r2;          // 0..31
          const int word = col * ESTRIDE + wv * 32 + ((d_ + 4 * wv) & 31);
          *(unsigned int*)(smem + word * 4) = pack2bf(v0, v1);
        }
      }
    }
    __syncthreads();

    // ---- attention 1: ALL 64 lanes (cc, hh, ll); b128 swizzle-quad loads ----
    {
      const int cc = lane >> 5;
      const int hh = (lane >> 2) & 7;
      const int ll = lane & 3;
      const unsigned int* Ew = (const unsigned int*)smem;
      const float* QLb = (const float*)(smem + QLOFF) + hh * 144 + ll * 36;
      const int cb = wv * 4;
      const unsigned int* EcA = Ew + (cb + 2 * cc) * ESTRIDE + hh * 32;
      const unsigned int* EcB = EcA + ESTRIDE;
      float s0 = 0.f, s1 = 0.f;
#pragma unroll
      for (int k = 0; k < 8; ++k) {
        const int q = (hh + k) & 7;               // swizzled quad: d = 4k+0..3
        const uint4 a4 = *(const uint4*)(EcA + q * 4);
        const uint4 b4 = *(const uint4*)(EcB + q * 4);
        const float4 qd = *(const float4*)(QLb + 4 * k);
        s0 += qd.x * lo_f(a4.x) + qd.y * lo_f(a4.y)
            + qd.z * lo_f(a4.z) + qd.w * lo_f(a4.w);
        s1 += qd.x * lo_f(b4.x) + qd.y * lo_f(b4.y)
            + qd.z * lo_f(b4.z) + qd.w * lo_f(b4.w);
      }
      const float sp0 = __shfl_xor(s0, 32);
      const float sp1 = __shfl_xor(s1, 32);
      const float sA = cc ? sp0 : s0;   // col cb+0
      const float sB = cc ? sp1 : s1;   // col cb+1
      const float sC = cc ? s0 : sp0;   // col cb+2
      const float sD = cc ? s1 : sp1;   // col cb+3
      const float mx = fmaxf(fmaxf(sA, sB), fmaxf(sC, sD));
      const float eA = __expf(sA - mx), eB = __expf(sB - mx);
      const float eC = __expf(sC - mx), eD = __expf(sD - mx);
      const float inv = 1.f / (eA + eB + eC + eD);
      const float a0 = eA * inv, a1 = eB * inv, a2_ = eC * inv, a3 = eD * inv;
      // each half-wave produces d in [16cc, 16cc+16): quads k = 4cc+k2
      const unsigned int* E0 = Ew + (cb + 0) * ESTRIDE + hh * 32;
      const unsigned int* E1 = E0 + ESTRIDE;
      const unsigned int* E2 = E1 + ESTRIDE;
      const unsigned int* E3 = E2 + ESTRIDE;
      unsigned char* LTb = smem + LTOFF + wv * 2112 + ll * LTSTR + hh * 64 + cc * 32;
#pragma unroll
      for (int k2 = 0; k2 < 4; ++k2) {
        const int q = (hh + cc * 4 + k2) & 7;
        const uint4 w0 = *(const uint4*)(E0 + q * 4);
        const uint4 w1 = *(const uint4*)(E1 + q * 4);
        const uint4 w2 = *(const uint4*)(E2 + q * 4);
        const uint4 w3 = *(const uint4*)(E3 + q * 4);
        const float4 qd = *(const float4*)(QLb + cc * 16 + 4 * k2);
        const float lv0 = qd.x + a0 * hi_f(w0.x) + a1 * hi_f(w1.x)
                               + a2_ * hi_f(w2.x) + a3 * hi_f(w3.x);
        const float lv1 = qd.y + a0 * hi_f(w0.y) + a1 * hi_f(w1.y)
                               + a2_ * hi_f(w2.y) + a3 * hi_f(w3.y);
        const float lv2 = qd.z + a0 * hi_f(w0.z) + a1 * hi_f(w1.z)
                               + a2_ * hi_f(w2.z) + a3 * hi_f(w3.z);
        const float lv3 = qd.w + a0 * hi_f(w0.w) + a1 * hi_f(w1.w)
                               + a2_ * hi_f(w2.w) + a3 * hi_f(w3.w);
        *(uint2*)(LTb + k2 * 8) =
            make_uint2(pack2bf(lv0, lv1), pack2bf(lv2, lv3));
      }
    }
    __syncthreads();

    // ---- D-write (all waves) into E's dead space, u32-pair-packed ----
#pragma unroll
    for (int i = 4; i < 6; ++i) {
#pragma unroll
      for (int jj = 0; jj < 2; ++jj) {
        const int col = jj * 16 + fm;
#pragma unroll
        for (int r2 = 0; r2 < 2; ++r2) {
          const int cdx = wv * 32 + (i - 4) * 16 + quad * 4 + r2 * 2;
          const float v0 = acc[i][hf * 2 + jj][r2 * 2]     + biasr[i][r2 * 2];
          const float v1 = acc[i][hf * 2 + jj][r2 * 2 + 1] + biasr[i][r2 * 2 + 1];
          *(unsigned int*)(smem + DOFF + col * DSTR + cdx * 2) = pack2bf(v0, v1);
        }
      }
    }
    // ---- spectral: in-place on LT; sin/cos once + angle-addition recurrence ----
    {
      unsigned char* LTp = smem + LTOFF + wv * 2112;
#pragma unroll
      for (int ii = 0; ii < 4; ++ii) {
        const int ic = ii * 64 + lane;  // channel i in [0,256)
        const float* wrp = weights + ic * 24;
        float wr_[24];
#pragma unroll
        for (int q2 = 0; q2 < 6; ++q2) {
          const float4 wq = *(const float4*)(wrp + q2 * 4);
          wr_[q2 * 4 + 0] = wq.x; wr_[q2 * 4 + 1] = wq.y;
          wr_[q2 * 4 + 2] = wq.z; wr_[q2 * 4 + 3] = wq.w;
        }
#pragma unroll
        for (int l2 = 0; l2 < 4; ++l2) {
          unsigned short* ps = (unsigned short*)(LTp + l2 * LTSTR + ic * 2);
          const float val = bf2f(*ps);
          const float th = val * 0.26179938779914946f;  // pi/12
          const float sn = __sinf(th), cs = __cosf(th);
          float av = wr_[12];  // m=0: cos term only
          float sm = sn, cm = cs;
#pragma unroll
          for (int mq = 1; mq <= 11; ++mq) {
            av += wr_[mq] * sm + wr_[12 + mq] * cm;
            if (mq < 11) {
              const float ns = sm * cs + cm * sn;
              cm = cm * cs - sm * sn;
              sm = ns;
            }
          }
          *ps = f2bf(av + val);
        }
      }
    }
    __syncthreads();

    // ---- attention 2 + xp + store: ALL 64 lanes (cc, hh, pp) ----
    {
      const int cc = lane >> 5;         // which 16-channel half
      const int hh = (lane >> 2) & 7;
      const int pp = lane & 3;
      const int col = wv * 4 + pp;
      const unsigned char* Db  = smem + DOFF + col * DSTR + hh * 64 + cc * 32;
      const unsigned char* LTp = smem + LTOFF + wv * 2112;
      union u4b { uint4 q; unsigned short us[8]; };
      float dq[16];
#pragma unroll
      for (int c8 = 0; c8 < 2; ++c8) {
        u4b td; td.q = *(const uint4*)(Db + c8 * 16);
#pragma unroll
        for (int e = 0; e < 8; ++e) dq[c8 * 8 + e] = bf2f(td.us[e]);
      }
      float sc2[4];
#pragma unroll
      for (int l2 = 0; l2 < 4; ++l2) {
        float sa = 0.f;
#pragma unroll
        for (int c8 = 0; c8 < 2; ++c8) {
          u4b tl; tl.q = *(const uint4*)(LTp + l2 * LTSTR + hh * 64 + cc * 32 + c8 * 16);
#pragma unroll
          for (int e = 0; e < 8; ++e) sa += dq[c8 * 8 + e] * bf2f(tl.us[e]);
        }
        sc2[l2] = sa + __shfl_xor(sa, 32);   // full 32-chan dot via pair exchange
      }
      const float mx2 = fmaxf(fmaxf(sc2[0], sc2[1]), fmaxf(sc2[2], sc2[3]));
      float ex[4];
#pragma unroll
      for (int l2 = 0; l2 < 4; ++l2) ex[l2] = __expf(sc2[l2] - mx2);
      const float inv2 = 1.f / (ex[0] + ex[1] + ex[2] + ex[3]);
      float aw[4];
#pragma unroll
      for (int l2 = 0; l2 < 4; ++l2) aw[l2] = ex[l2] * inv2;

      const int hpf = (blockIdx.x & 63) * 16 + hf * 8 + wv;  // Hp index
      const int hg  = h0 + hf * 32 + wv * 4 + pp;            // h index
      float* ob = out + bb * 1048576 + pp * 262144 + hpf * 256 + hh * 32 + cc * 16;
      const float* xc = x + bb * 1048576 + (hh * 32 + cc * 16) * 4096 + hg;
#pragma unroll
      for (int c8 = 0; c8 < 2; ++c8) {
        float ov[8];
#pragma unroll
        for (int e = 0; e < 8; ++e) ov[e] = 0.f;
#pragma unroll
        for (int l2 = 0; l2 < 4; ++l2) {
          u4b tl; tl.q = *(const uint4*)(LTp + l2 * LTSTR + hh * 64 + cc * 32 + c8 * 16);
#pragma unroll
          for (int e = 0; e < 8; ++e) ov[e] += aw[l2] * bf2f(tl.us[e]);
        }
#pragma unroll
        for (int e = 0; e < 8; ++e) ov[e] += xc[(c8 * 8 + e) * 4096];
        *(float4*)(ob + c8 * 8)     = make_float4(ov[0], ov[1], ov[2], ov[3]);
        *(float4*)(ob + c8 * 8 + 4) = make_float4(ov[4], ov[5], ov[6], ov[7]);
      }
    }
    __syncthreads();
  }
}

extern "C" void kernel_launch(void* const* d_in, const int* in_sizes, int n_in,
                              void* d_out, int out_size, void* d_ws, size_t ws_size,
                              hipStream_t stream) {
  const float* x       = (const float*)d_in[0];
  const float* weights = (const float*)d_in[1];
  const float* latent  = (const float*)d_in[2];
  const float* enc_w   = (const float*)d_in[3];
  const float* enc_b   = (const float*)d_in[4];
  const float* dec_w   = (const float*)d_in[5];
  const float* dec_b   = (const float*)d_in[6];
  unsigned short* Wb   = (unsigned short*)d_ws;  // 768*256 bf16 = 384 KB (frag order)
  float* outp          = (float*)d_out;

  wconv_kernel<<<96, 256, 0, stream>>>(enc_w, dec_w, Wb);
  nsb_kernel<<<2048, 512, 0, stream>>>(x, weights, latent, enc_b, dec_b, Wb, outp);
}

// Round 5
// 482.089 us; speedup vs baseline: 1.2889x; 1.2889x over previous
//
#include <hip/hip_runtime.h>

// NeuralSpectralBlock1d on MI355X (gfx950)
// B=32, C=256, H=4096, PATCH=4, HEAD=8, DH=32, NT=4, NB=12
// v5 = v4 with spill fix (rolled attn1 loops) + uint2-paired E/D writes.
//   v4 post-mortem: fully-unrolled attn1 b128 loops kept ~60 extra VGPRs
//   live -> allocator hit its 128 cap -> acc spilled to scratch
//   (+620 MB/dispatch HBM traffic, 329 -> 478 us). Fix: cap live uint4s
//   via unroll pragmas; everything else of v4 kept.
//
//   wconv_kernel: enc_w(512x256) ++ dec_w(256x256) -> bf16 Wb in d_ws,
//                 MFMA fragment order: elem = ((m16*8+kt)*64 + quad*16+fm)*8 + j
//   nsb_kernel:   grid 2048 = 32 b * 64 col-chunks; block 512 thr (8 waves)
//     stage:   c-major: lane=h, 4 consecutive channels/thread/round ->
//              ds_write_b64 at lane*536 (16 bank starts; conflict-free),
//              global side = 4 scalar dword loads, each 256B coalesced.
//     phase 1: Y = Wb @ X barrier-free; wave owns enc tiles {4w..4w+3} and
//              dec tiles {32+2w, 33+2w} -> E and D writes engage all 8 waves.
//     phase 2: per half (32 cols): E-write (uint2-paired) -> attn1 (b128
//              swizzle-quad loads, rolled) -> D-write (uint2-paired) +
//              spectral -> attn2 + residual + store.
//
// LDS map (54784 B):
//   stage: Bl [0,34304)       64 h * 536 B (256 bf16 ch + pad)
//   E:  [0,33280)   32 cols * 260 words; (k,v) pair word, (d+4h)&31 swizzle,
//                   4-word pad/col for 16B-aligned b128 quad reads
//   D:  [0,16896)   32 cols * 528 B (overlay; E dead)
//   LT: [33280,50176) 8 patches * 4 l * 528 B
//   QL: [50176,54784) latent fp32 [h][l][36] (pad 36 -> aligned float4 reads)

typedef __attribute__((ext_vector_type(8))) short short8;
typedef __attribute__((ext_vector_type(4))) float f32x4;

#define BSTRIDE 536
#define ESTRIDE 260
#define DSTR    528
#define LTSTR   528
#define DOFF    0
#define LTOFF   33280
#define QLOFF   50176

__device__ __forceinline__ unsigned short f2bf(float f) {
  union { float f; unsigned int u; } c; c.f = f;
  unsigned int u = c.u + 0x7FFFu + ((c.u >> 16) & 1u);
  return (unsigned short)(u >> 16);
}
__device__ __forceinline__ float bf2f(unsigned short s) {
  union { unsigned int u; float f; } c; c.u = ((unsigned int)s) << 16;
  return c.f;
}
__device__ __forceinline__ unsigned int pack2bf(float lo, float hi) {
  return (unsigned int)f2bf(lo) | ((unsigned int)f2bf(hi) << 16);
}
__device__ __forceinline__ float lo_f(unsigned int u) {
  union { unsigned int x; float f; } c; c.x = u << 16; return c.f;
}
__device__ __forceinline__ float hi_f(unsigned int u) {
  union { unsigned int x; float f; } c; c.x = u & 0xffff0000u; return c.f;
}

// Wb fragment layout: element index = ((m16*8 + kt)*64 + quad*16 + fm)*8 + j
// source: W[row = m16*16 + fm][k = kt*32 + quad*8 + j]
__global__ void wconv_kernel(const float* __restrict__ enc_w,
                             const float* __restrict__ dec_w,
                             unsigned short* __restrict__ Wb) {
  const int g   = blockIdx.x * 256 + threadIdx.x;  // 96*256 = 24576 = 196608/8
  const int blk = g >> 6;        // m16*8 + kt
  const int lp  = g & 63;        // quad*16 + fm
  const int m16 = blk >> 3, kt = blk & 7;
  const int fm  = lp & 15, quad = lp >> 4;
  const int row = m16 * 16 + fm;
  const int k   = kt * 32 + quad * 8;
  const float* src = (row < 512) ? (enc_w + row * 256 + k)
                                 : (dec_w + (row - 512) * 256 + k);
  const float4 v0 = *(const float4*)(src);
  const float4 v1 = *(const float4*)(src + 4);
  ushort4 o0, o1;
  o0.x = f2bf(v0.x); o0.y = f2bf(v0.y); o0.z = f2bf(v0.z); o0.w = f2bf(v0.w);
  o1.x = f2bf(v1.x); o1.y = f2bf(v1.y); o1.z = f2bf(v1.z); o1.w = f2bf(v1.w);
  *(ushort4*)(Wb + g * 8)     = o0;
  *(ushort4*)(Wb + g * 8 + 4) = o1;
}

__global__ __launch_bounds__(512) void nsb_kernel(
    const float* __restrict__ x,
    const float* __restrict__ weights,
    const float* __restrict__ latent,
    const float* __restrict__ enc_b,
    const float* __restrict__ dec_b,
    const unsigned short* __restrict__ Wb,
    float* __restrict__ out)
{
  __shared__ __attribute__((aligned(16))) unsigned char smem[54784];
  const int t    = threadIdx.x;
  const int wv   = t >> 6;       // wave 0..7
  const int lane = t & 63;
  const int fm   = lane & 15;    // mfma m/n index
  const int quad = lane >> 4;    // mfma k-group / row-quad
  const int bb   = blockIdx.x >> 6;          // batch
  const int h0   = (blockIdx.x & 63) << 6;   // column base in H

  f32x4 acc[6][4];
#pragma unroll
  for (int i = 0; i < 6; ++i)
#pragma unroll
    for (int j = 0; j < 4; ++j)
      acc[i][j] = f32x4{0.f, 0.f, 0.f, 0.f};

  // ---- stage: c-major, conflict-free.  lane = h; 4 consecutive ch/round ----
  {
#pragma unroll
    for (int rd = 0; rd < 8; ++rd) {
      const int c0 = rd * 32 + wv * 4;
      const float* xp = x + (bb * 256 + c0) * 4096 + h0 + lane;
      const float a = xp[0];
      const float b = xp[4096];
      const float c = xp[8192];
      const float d = xp[12288];
      *(uint2*)(smem + lane * BSTRIDE + c0 * 2) =
          make_uint2(pack2bf(a, b), pack2bf(c, d));
    }
  }
  {
    const int e0 = t * 2;
    const float2 lv = *(const float2*)(latent + e0);
    int h_ = e0 >> 7, l_ = (e0 >> 5) & 3, d_ = e0 & 31;
    *(float*)(smem + QLOFF + (h_ * 144 + l_ * 36 + d_) * 4) = lv.x;
    const int e1 = e0 + 1;
    h_ = e1 >> 7; l_ = (e1 >> 5) & 3; d_ = e1 & 31;
    *(float*)(smem + QLOFF + (h_ * 144 + l_ * 36 + d_) * 4) = lv.y;
  }
  __syncthreads();

  // ---- phase 1: GEMM Y = W @ X, barrier-free; balanced tile map ----
  // wave tiles: i<4 -> enc tile (wv*4+i); i in {4,5} -> dec tile (32+2wv+i-4)
  {
    const unsigned char* Bb = smem + fm * BSTRIDE + quad * 16;
    const unsigned short* ApE = Wb + (wv * 4) * 4096 + lane * 8;
    const unsigned short* ApD = Wb + (32 + wv * 2) * 4096 + lane * 8;
#pragma unroll
    for (int kt = 0; kt < 8; ++kt) {
      short8 bfrag[4];
#pragma unroll
      for (int j = 0; j < 4; ++j) {
        const unsigned char* p = Bb + j * 16 * BSTRIDE + kt * 64;
        union { short8 s; uint2 u[2]; } tb;
        tb.u[0] = *(const uint2*)(p);
        tb.u[1] = *(const uint2*)(p + 8);
        bfrag[j] = tb.s;
      }
#pragma unroll
      for (int i = 0; i < 4; ++i) {
        const short8 afrag = *(const short8*)(ApE + i * 4096 + kt * 512);
#pragma unroll
        for (int j = 0; j < 4; ++j)
          acc[i][j] = __builtin_amdgcn_mfma_f32_16x16x32_bf16(afrag, bfrag[j], acc[i][j], 0, 0, 0);
      }
#pragma unroll
      for (int i = 0; i < 2; ++i) {
        const short8 afrag = *(const short8*)(ApD + i * 4096 + kt * 512);
#pragma unroll
        for (int j = 0; j < 4; ++j)
          acc[4 + i][j] = __builtin_amdgcn_mfma_f32_16x16x32_bf16(afrag, bfrag[j], acc[4 + i][j], 0, 0, 0);
      }
    }
  }
  __syncthreads();   // Bl dead after this; E overlays it

  // ---- epilogue setup: bias registers (balanced map) ----
  float biasr[6][4];
#pragma unroll
  for (int i = 0; i < 4; ++i)
#pragma unroll
    for (int r = 0; r < 4; ++r)
      biasr[i][r] = enc_b[wv * 64 + i * 16 + quad * 4 + r];
#pragma unroll
  for (int i = 4; i < 6; ++i)
#pragma unroll
    for (int r = 0; r < 4; ++r)
      biasr[i][r] = dec_b[wv * 32 + (i - 4) * 16 + quad * 4 + r];

#pragma unroll
  for (int hf = 0; hf < 2; ++hf) {
    // ---- E-write: all waves; wave w writes head h_=w only; uint2-paired ----
    // words swz, swz+1 are adjacent (d0 even => swizzle never wraps in-pair)
#pragma unroll
    for (int i = 0; i < 4; ++i) {
      const int d0  = i * 8 + quad * 2;            // even
      const int swz = (d0 + 4 * wv) & 31;          // even too
#pragma unroll
      for (int jj = 0; jj < 2; ++jj) {
        const int col = jj * 16 + fm;  // 0..31 within half
        const unsigned int w0 = pack2bf(acc[i][hf * 2 + jj][0] + biasr[i][0],
                                        acc[i][hf * 2 + jj][1] + biasr[i][1]);
        const unsigned int w1 = pack2bf(acc[i][hf * 2 + jj][2] + biasr[i][2],
                                        acc[i][hf * 2 + jj][3] + biasr[i][3]);
        *(uint2*)(smem + (col * ESTRIDE + wv * 32 + swz) * 4) = make_uint2(w0, w1);
      }
    }
    __syncthreads();

    // ---- attention 1: ALL 64 lanes (cc, hh, ll); b128 swizzle-quad loads ----
    // loops kept rolled (unroll 2 / unroll 1) to cap live uint4s -> no spill
    {
      const int cc = lane >> 5;
      const int hh = (lane >> 2) & 7;
      const int ll = lane & 3;
      const unsigned int* Ew = (const unsigned int*)smem;
      const float* QLb = (const float*)(smem + QLOFF) + hh * 144 + ll * 36;
      const int cb = wv * 4;
      const unsigned int* EcA = Ew + (cb + 2 * cc) * ESTRIDE + hh * 32;
      const unsigned int* EcB = EcA + ESTRIDE;
      float s0 = 0.f, s1 = 0.f;
#pragma unroll 2
      for (int k = 0; k < 8; ++k) {
        const int q = (hh + k) & 7;               // swizzled quad: d = 4k+0..3
        const uint4 a4 = *(const uint4*)(EcA + q * 4);
        const uint4 b4 = *(const uint4*)(EcB + q * 4);
        const float4 qd = *(const float4*)(QLb + 4 * k);
        s0 += qd.x * lo_f(a4.x) + qd.y * lo_f(a4.y)
            + qd.z * lo_f(a4.z) + qd.w * lo_f(a4.w);
        s1 += qd.x * lo_f(b4.x) + qd.y * lo_f(b4.y)
            + qd.z * lo_f(b4.z) + qd.w * lo_f(b4.w);
      }
      const float sp0 = __shfl_xor(s0, 32);
      const float sp1 = __shfl_xor(s1, 32);
      const float sA = cc ? sp0 : s0;   // col cb+0
      const float sB = cc ? sp1 : s1;   // col cb+1
      const float sC = cc ? s0 : sp0;   // col cb+2
      const float sD = cc ? s1 : sp1;   // col cb+3
      const float mx = fmaxf(fmaxf(sA, sB), fmaxf(sC, sD));
      const float eA = __expf(sA - mx), eB = __expf(sB - mx);
      const float eC = __expf(sC - mx), eD = __expf(sD - mx);
      const float inv = 1.f / (eA + eB + eC + eD);
      const float a0 = eA * inv, a1 = eB * inv, a2_ = eC * inv, a3 = eD * inv;
      // each half-wave produces d in [16cc, 16cc+16): quads k = 4cc+k2
      const unsigned int* E0 = Ew + (cb + 0) * ESTRIDE + hh * 32;
      const unsigned int* E1 = E0 + ESTRIDE;
      const unsigned int* E2 = E1 + ESTRIDE;
      const unsigned int* E3 = E2 + ESTRIDE;
      unsigned char* LTb = smem + LTOFF + wv * 2112 + ll * LTSTR + hh * 64 + cc * 32;
#pragma unroll 1
      for (int k2 = 0; k2 < 4; ++k2) {
        const int q = (hh + cc * 4 + k2) & 7;
        const uint4 w0 = *(const uint4*)(E0 + q * 4);
        const uint4 w1 = *(const uint4*)(E1 + q * 4);
        const uint4 w2 = *(const uint4*)(E2 + q * 4);
        const uint4 w3 = *(const uint4*)(E3 + q * 4);
        const float4 qd = *(const float4*)(QLb + cc * 16 + 4 * k2);
        const float lv0 = qd.x + a0 * hi_f(w0.x) + a1 * hi_f(w1.x)
                               + a2_ * hi_f(w2.x) + a3 * hi_f(w3.x);
        const float lv1 = qd.y + a0 * hi_f(w0.y) + a1 * hi_f(w1.y)
                               + a2_ * hi_f(w2.y) + a3 * hi_f(w3.y);
        const float lv2 = qd.z + a0 * hi_f(w0.z) + a1 * hi_f(w1.z)
                               + a2_ * hi_f(w2.z) + a3 * hi_f(w3.z);
        const float lv3 = qd.w + a0 * hi_f(w0.w) + a1 * hi_f(w1.w)
                               + a2_ * hi_f(w2.w) + a3 * hi_f(w3.w);
        *(uint2*)(LTb + k2 * 8) =
            make_uint2(pack2bf(lv0, lv1), pack2bf(lv2, lv3));
      }
    }
    __syncthreads();

    // ---- D-write (all waves) into E's dead space, uint2-paired ----
#pragma unroll
    for (int i = 4; i < 6; ++i) {
      const int c0 = wv * 32 + (i - 4) * 16 + quad * 4;   // multiple of 4
#pragma unroll
      for (int jj = 0; jj < 2; ++jj) {
        const int col = jj * 16 + fm;
        const unsigned int w0 = pack2bf(acc[i][hf * 2 + jj][0] + biasr[i][0],
                                        acc[i][hf * 2 + jj][1] + biasr[i][1]);
        const unsigned int w1 = pack2bf(acc[i][hf * 2 + jj][2] + biasr[i][2],
                                        acc[i][hf * 2 + jj][3] + biasr[i][3]);
        *(uint2*)(smem + DOFF + col * DSTR + c0 * 2) = make_uint2(w0, w1);
      }
    }
    // ---- spectral: in-place on LT; sin/cos once + angle-addition recurrence ----
    {
      unsigned char* LTp = smem + LTOFF + wv * 2112;
#pragma unroll
      for (int ii = 0; ii < 4; ++ii) {
        const int ic = ii * 64 + lane;  // channel i in [0,256)
        const float* wrp = weights + ic * 24;
        float wr_[24];
#pragma unroll
        for (int q2 = 0; q2 < 6; ++q2) {
          const float4 wq = *(const float4*)(wrp + q2 * 4);
          wr_[q2 * 4 + 0] = wq.x; wr_[q2 * 4 + 1] = wq.y;
          wr_[q2 * 4 + 2] = wq.z; wr_[q2 * 4 + 3] = wq.w;
        }
#pragma unroll
        for (int l2 = 0; l2 < 4; ++l2) {
          unsigned short* ps = (unsigned short*)(LTp + l2 * LTSTR + ic * 2);
          const float val = bf2f(*ps);
          const float th = val * 0.26179938779914946f;  // pi/12
          const float sn = __sinf(th), cs = __cosf(th);
          float av = wr_[12];  // m=0: cos term only
          float sm = sn, cm = cs;
#pragma unroll
          for (int mq = 1; mq <= 11; ++mq) {
            av += wr_[mq] * sm + wr_[12 + mq] * cm;
            if (mq < 11) {
              const float ns = sm * cs + cm * sn;
              cm = cm * cs - sm * sn;
              sm = ns;
            }
          }
          *ps = f2bf(av + val);
        }
      }
    }
    __syncthreads();

    // ---- attention 2 + xp + store: ALL 64 lanes (cc, hh, pp) ----
    {
      const int cc = lane >> 5;         // which 16-channel half
      const int hh = (lane >> 2) & 7;
      const int pp = lane & 3;
      const int col = wv * 4 + pp;
      const unsigned char* Db  = smem + DOFF + col * DSTR + hh * 64 + cc * 32;
      const unsigned char* LTp = smem + LTOFF + wv * 2112;
      union u4b { uint4 q; unsigned short us[8]; };
      float dq[16];
#pragma unroll
      for (int c8 = 0; c8 < 2; ++c8) {
        u4b td; td.q = *(const uint4*)(Db + c8 * 16);
#pragma unroll
        for (int e = 0; e < 8; ++e) dq[c8 * 8 + e] = bf2f(td.us[e]);
      }
      float sc2[4];
#pragma unroll
      for (int l2 = 0; l2 < 4; ++l2) {
        float sa = 0.f;
#pragma unroll
        for (int c8 = 0; c8 < 2; ++c8) {
          u4b tl; tl.q = *(const uint4*)(LTp + l2 * LTSTR + hh * 64 + cc * 32 + c8 * 16);
#pragma unroll
          for (int e = 0; e < 8; ++e) sa += dq[c8 * 8 + e] * bf2f(tl.us[e]);
        }
        sc2[l2] = sa + __shfl_xor(sa, 32);   // full 32-chan dot via pair exchange
      }
      const float mx2 = fmaxf(fmaxf(sc2[0], sc2[1]), fmaxf(sc2[2], sc2[3]));
      float ex[4];
#pragma unroll
      for (int l2 = 0; l2 < 4; ++l2) ex[l2] = __expf(sc2[l2] - mx2);
      const float inv2 = 1.f / (ex[0] + ex[1] + ex[2] + ex[3]);
      float aw[4];
#pragma unroll
      for (int l2 = 0; l2 < 4; ++l2) aw[l2] = ex[l2] * inv2;

      const int hpf = (blockIdx.x & 63) * 16 + hf * 8 + wv;  // Hp index
      const int hg  = h0 + hf * 32 + wv * 4 + pp;            // h index
      float* ob = out + bb * 1048576 + pp * 262144 + hpf * 256 + hh * 32 + cc * 16;
      const float* xc = x + bb * 1048576 + (hh * 32 + cc * 16) * 4096 + hg;
#pragma unroll
      for (int c8 = 0; c8 < 2; ++c8) {
        float ov[8];
#pragma unroll
        for (int e = 0; e < 8; ++e) ov[e] = 0.f;
#pragma unroll
        for (int l2 = 0; l2 < 4; ++l2) {
          u4b tl; tl.q = *(const uint4*)(LTp + l2 * LTSTR + hh * 64 + cc * 32 + c8 * 16);
#pragma unroll
          for (int e = 0; e < 8; ++e) ov[e] += aw[l2] * bf2f(tl.us[e]);
        }
#pragma unroll
        for (int e = 0; e < 8; ++e) ov[e] += xc[(c8 * 8 + e) * 4096];
        *(float4*)(ob + c8 * 8)     = make_float4(ov[0], ov[1], ov[2], ov[3]);
        *(float4*)(ob + c8 * 8 + 4) = make_float4(ov[4], ov[5], ov[6], ov[7]);
      }
    }
    __syncthreads();
  }
}

extern "C" void kernel_launch(void* const* d_in, const int* in_sizes, int n_in,
                              void* d_out, int out_size, void* d_ws, size_t ws_size,
                              hipStream_t stream) {
  const float* x       = (const float*)d_in[0];
  const float* weights = (const float*)d_in[1];
  const float* latent  = (const float*)d_in[2];
  const float* enc_w   = (const float*)d_in[3];
  const float* enc_b   = (const float*)d_in[4];
  const float* dec_w   = (const float*)d_in[5];
  const float* dec_b   = (const float*)d_in[6];
  unsigned short* Wb   = (unsigned short*)d_ws;  // 768*256 bf16 = 384 KB (frag order)
  float* outp          = (float*)d_out;

  wconv_kernel<<<96, 256, 0, stream>>>(enc_w, dec_w, Wb);
  nsb_kernel<<<2048, 512, 0, stream>>>(x, weights, latent, enc_b, dec_b, Wb, outp);
}

// Round 7
// 396.115 us; speedup vs baseline: 1.5687x; 1.2170x over previous
//
#include <hip/hip_runtime.h>

// NeuralSpectralBlock1d on MI355X (gfx950)
// B=32, C=256, H=4096, PATCH=4, HEAD=8, DH=32, NT=4, NB=12
// v6b: occupancy fix (resubmit of v6 after infra failure, with corrected
//   launch bounds). Occupancy was pinned at 23.4% = 2 waves/SIMD because
//   VGPR_Count excludes AGPRs: v5 = 92 VGPR + 96 AGPR (acc[6][4]) = 188.
//   Fix: 32-col blocks (grid 4096), acc[6][2]=48 AGPR, single-pass epilogue,
//   late bias loads -> total ~130; __launch_bounds__(512,4) = 4 waves/EU
//   -> k = 4*4/(512/64) = 2 blocks/CU -> 128-total cap (v2 evidence: this
//   spelling caps total regs at 128; demand must fit or it spills, so acc
//   was halved first).
//   Also: chunk-swizzle LT and D (16B chunk c=[hh|cc|c8] stored at slot
//   (c&3)<<3|c>>2) -> attn2 b128 reads were 4-8-way conflicted -> minimum.
//
//   wconv_kernel: enc_w(512x256) ++ dec_w(256x256) -> bf16 Wb (frag order:
//                 elem = ((m16*8+kt)*64 + quad*16+fm)*8 + j)
//   nsb_kernel:   grid 4096 = 32 b * 128 col-chunks (32 cols); 512 thr
//     stage:   c-major, h=t&31, 4 ch/thread/round -> ds_write_b64, conflict-free
//     GEMM:    Y(768x32) = Wb @ X barrier-free; wave: enc tiles {4w..4w+3},
//              dec tiles {32+2w,33+2w}; acc[6][2]
//     epilog (single pass, 8 patches <-> 8 waves):
//              E-write -> attn1 (b128 swizzle-quad) -> D-write + spectral
//              -> attn2 + residual + store
//
// LDS map (54784 B):
//   stage: Bl [0,17152)   32 h * 536 B
//   E:  [0,33280)   32 cols * 260 words; (k,v) pair word, (d+4h)&31 swizzle
//   D:  [0,16896)   32 cols * 528 B, chunk-swizzled (overlay; E dead)
//   LT: [33280,50176) 8 patches * 4 l * 528 B, chunk-swizzled
//   QL: [50176,54784) latent fp32 [h][l][36]

typedef __attribute__((ext_vector_type(8))) short short8;
typedef __attribute__((ext_vector_type(4))) float f32x4;

#define BSTRIDE 536
#define ESTRIDE 260
#define DSTR    528
#define LTSTR   528
#define DOFF    0
#define LTOFF   33280
#define QLOFF   50176

__device__ __forceinline__ unsigned short f2bf(float f) {
  union { float f; unsigned int u; } c; c.f = f;
  unsigned int u = c.u + 0x7FFFu + ((c.u >> 16) & 1u);
  return (unsigned short)(u >> 16);
}
__device__ __forceinline__ float bf2f(unsigned short s) {
  union { unsigned int u; float f; } c; c.u = ((unsigned int)s) << 16;
  return c.f;
}
__device__ __forceinline__ unsigned int pack2bf(float lo, float hi) {
  return (unsigned int)f2bf(lo) | ((unsigned int)f2bf(hi) << 16);
}
__device__ __forceinline__ float lo_f(unsigned int u) {
  union { unsigned int x; float f; } c; c.x = u << 16; return c.f;
}
__device__ __forceinline__ float hi_f(unsigned int u) {
  union { unsigned int x; float f; } c; c.x = u & 0xffff0000u; return c.f;
}
// chunk swizzle for LT/D rows (256 ch * 2B = 32 x 16B chunks):
// chunk c = ch>>3 (bits [hh2 hh1 hh0 cc c8]) stored at slot (c&3)<<3 | c>>2
__device__ __forceinline__ int ltswz(int ch) {
  const int c = ch >> 3;
  return ((c & 3) << 7) | ((c >> 2) << 4) | ((ch & 7) << 1);
}

// Wb fragment layout: element index = ((m16*8 + kt)*64 + quad*16 + fm)*8 + j
__global__ void wconv_kernel(const float* __restrict__ enc_w,
                             const float* __restrict__ dec_w,
                             unsigned short* __restrict__ Wb) {
  const int g   = blockIdx.x * 256 + threadIdx.x;  // 96*256 = 24576 = 196608/8
  const int blk = g >> 6;        // m16*8 + kt
  const int lp  = g & 63;        // quad*16 + fm
  const int m16 = blk >> 3, kt = blk & 7;
  const int fm  = lp & 15, quad = lp >> 4;
  const int row = m16 * 16 + fm;
  const int k   = kt * 32 + quad * 8;
  const float* src = (row < 512) ? (enc_w + row * 256 + k)
                                 : (dec_w + (row - 512) * 256 + k);
  const float4 v0 = *(const float4*)(src);
  const float4 v1 = *(const float4*)(src + 4);
  ushort4 o0, o1;
  o0.x = f2bf(v0.x); o0.y = f2bf(v0.y); o0.z = f2bf(v0.z); o0.w = f2bf(v0.w);
  o1.x = f2bf(v1.x); o1.y = f2bf(v1.y); o1.z = f2bf(v1.z); o1.w = f2bf(v1.w);
  *(ushort4*)(Wb + g * 8)     = o0;
  *(ushort4*)(Wb + g * 8 + 4) = o1;
}

__global__ __launch_bounds__(512, 4) void nsb_kernel(
    const float* __restrict__ x,
    const float* __restrict__ weights,
    const float* __restrict__ latent,
    const float* __restrict__ enc_b,
    const float* __restrict__ dec_b,
    const unsigned short* __restrict__ Wb,
    float* __restrict__ out)
{
  __shared__ __attribute__((aligned(16))) unsigned char smem[54784];
  const int t    = threadIdx.x;
  const int wv   = t >> 6;       // wave 0..7
  const int lane = t & 63;
  const int fm   = lane & 15;    // mfma m/n index
  const int quad = lane >> 4;    // mfma k-group / row-quad
  const int bb   = blockIdx.x >> 7;           // batch
  const int chnk = blockIdx.x & 127;          // col chunk
  const int h0   = chnk << 5;                 // column base in H (32 cols)

  f32x4 acc[6][2];
#pragma unroll
  for (int i = 0; i < 6; ++i)
#pragma unroll
    for (int j = 0; j < 2; ++j)
      acc[i][j] = f32x4{0.f, 0.f, 0.f, 0.f};

  // ---- stage: c-major, conflict-free. h = t&31; 4 consecutive ch/round ----
  {
    const int sh = t & 31, cg = t >> 5;   // cg 0..15
#pragma unroll
    for (int rd = 0; rd < 4; ++rd) {
      const int c0 = rd * 64 + cg * 4;
      const float* xp = x + (bb * 256 + c0) * 4096 + h0 + sh;
      const float a = xp[0];
      const float b = xp[4096];
      const float c = xp[8192];
      const float d = xp[12288];
      *(uint2*)(smem + sh * BSTRIDE + c0 * 2) =
          make_uint2(pack2bf(a, b), pack2bf(c, d));
    }
  }
  {
    const int e0 = t * 2;
    const float2 lv = *(const float2*)(latent + e0);
    int h_ = e0 >> 7, l_ = (e0 >> 5) & 3, d_ = e0 & 31;
    *(float*)(smem + QLOFF + (h_ * 144 + l_ * 36 + d_) * 4) = lv.x;
    const int e1 = e0 + 1;
    h_ = e1 >> 7; l_ = (e1 >> 5) & 3; d_ = e1 & 31;
    *(float*)(smem + QLOFF + (h_ * 144 + l_ * 36 + d_) * 4) = lv.y;
  }
  __syncthreads();

  // ---- GEMM Y = W @ X, barrier-free; balanced tile map ----
  {
    const unsigned char* Bb = smem + fm * BSTRIDE + quad * 16;
    const unsigned short* ApE = Wb + (wv * 4) * 4096 + lane * 8;
    const unsigned short* ApD = Wb + (32 + wv * 2) * 4096 + lane * 8;
#pragma unroll
    for (int kt = 0; kt < 8; ++kt) {
      short8 bfrag[2];
#pragma unroll
      for (int j = 0; j < 2; ++j) {
        const unsigned char* p = Bb + j * 16 * BSTRIDE + kt * 64;
        union { short8 s; uint2 u[2]; } tb;
        tb.u[0] = *(const uint2*)(p);
        tb.u[1] = *(const uint2*)(p + 8);
        bfrag[j] = tb.s;
      }
#pragma unroll
      for (int i = 0; i < 4; ++i) {
        const short8 afrag = *(const short8*)(ApE + i * 4096 + kt * 512);
#pragma unroll
        for (int j = 0; j < 2; ++j)
          acc[i][j] = __builtin_amdgcn_mfma_f32_16x16x32_bf16(afrag, bfrag[j], acc[i][j], 0, 0, 0);
      }
#pragma unroll
      for (int i = 0; i < 2; ++i) {
        const short8 afrag = *(const short8*)(ApD + i * 4096 + kt * 512);
#pragma unroll
        for (int j = 0; j < 2; ++j)
          acc[4 + i][j] = __builtin_amdgcn_mfma_f32_16x16x32_bf16(afrag, bfrag[j], acc[4 + i][j], 0, 0, 0);
      }
    }
  }
  __syncthreads();   // Bl dead after this; E overlays it

  // ---- E-write: wave w = head w; (k,v) pair word, (d+4h)&31 swizzle ----
#pragma unroll
  for (int i = 0; i < 4; ++i) {
    const float4 be = *(const float4*)(enc_b + wv * 64 + i * 16 + quad * 4);
    const int d0  = i * 8 + quad * 2;            // even
    const int swz = (d0 + 4 * wv) & 31;          // even; pair never wraps
#pragma unroll
    for (int j = 0; j < 2; ++j) {
      const int col = j * 16 + fm;
      const unsigned int w0 = pack2bf(acc[i][j][0] + be.x, acc[i][j][1] + be.y);
      const unsigned int w1 = pack2bf(acc[i][j][2] + be.z, acc[i][j][3] + be.w);
      *(uint2*)(smem + (col * ESTRIDE + wv * 32 + swz) * 4) = make_uint2(w0, w1);
    }
  }
  __syncthreads();

  // ---- attention 1: ALL 64 lanes (cc, hh, ll); b128 swizzle-quad loads ----
  {
    const int cc = lane >> 5;
    const int hh = (lane >> 2) & 7;
    const int ll = lane & 3;
    const unsigned int* Ew = (const unsigned int*)smem;
    const float* QLb = (const float*)(smem + QLOFF) + hh * 144 + ll * 36;
    const int cb = wv * 4;
    const unsigned int* EcA = Ew + (cb + 2 * cc) * ESTRIDE + hh * 32;
    const unsigned int* EcB = EcA + ESTRIDE;
    float s0 = 0.f, s1 = 0.f;
#pragma unroll 2
    for (int k = 0; k < 8; ++k) {
      const int q = (hh + k) & 7;               // swizzled quad: d = 4k+0..3
      const uint4 a4 = *(const uint4*)(EcA + q * 4);
      const uint4 b4 = *(const uint4*)(EcB + q * 4);
      const float4 qd = *(const float4*)(QLb + 4 * k);
      s0 += qd.x * lo_f(a4.x) + qd.y * lo_f(a4.y)
          + qd.z * lo_f(a4.z) + qd.w * lo_f(a4.w);
      s1 += qd.x * lo_f(b4.x) + qd.y * lo_f(b4.y)
          + qd.z * lo_f(b4.z) + qd.w * lo_f(b4.w);
    }
    const float sp0 = __shfl_xor(s0, 32);
    const float sp1 = __shfl_xor(s1, 32);
    const float sA = cc ? sp0 : s0;   // col cb+0
    const float sB = cc ? sp1 : s1;   // col cb+1
    const float sC = cc ? s0 : sp0;   // col cb+2
    const float sD = cc ? s1 : sp1;   // col cb+3
    const float mx = fmaxf(fmaxf(sA, sB), fmaxf(sC, sD));
    const float eA = __expf(sA - mx), eB = __expf(sB - mx);
    const float eC = __expf(sC - mx), eD = __expf(sD - mx);
    const float inv = 1.f / (eA + eB + eC + eD);
    const float a0 = eA * inv, a1 = eB * inv, a2_ = eC * inv, a3 = eD * inv;
    // each half-wave produces d in [16cc, 16cc+16): quads k = 4cc+k2
    const unsigned int* E0 = Ew + (cb + 0) * ESTRIDE + hh * 32;
    const unsigned int* E1 = E0 + ESTRIDE;
    const unsigned int* E2 = E1 + ESTRIDE;
    const unsigned int* E3 = E2 + ESTRIDE;
    unsigned char* LTb = smem + LTOFF + wv * 2112 + ll * LTSTR;
#pragma unroll 1
    for (int k2 = 0; k2 < 4; ++k2) {
      const int q = (hh + cc * 4 + k2) & 7;
      const uint4 w0 = *(const uint4*)(E0 + q * 4);
      const uint4 w1 = *(const uint4*)(E1 + q * 4);
      const uint4 w2 = *(const uint4*)(E2 + q * 4);
      const uint4 w3 = *(const uint4*)(E3 + q * 4);
      const float4 qd = *(const float4*)(QLb + cc * 16 + 4 * k2);
      const float lv0 = qd.x + a0 * hi_f(w0.x) + a1 * hi_f(w1.x)
                             + a2_ * hi_f(w2.x) + a3 * hi_f(w3.x);
      const float lv1 = qd.y + a0 * hi_f(w0.y) + a1 * hi_f(w1.y)
                             + a2_ * hi_f(w2.y) + a3 * hi_f(w3.y);
      const float lv2 = qd.z + a0 * hi_f(w0.z) + a1 * hi_f(w1.z)
                             + a2_ * hi_f(w2.z) + a3 * hi_f(w3.z);
      const float lv3 = qd.w + a0 * hi_f(w0.w) + a1 * hi_f(w1.w)
                             + a2_ * hi_f(w2.w) + a3 * hi_f(w3.w);
      // ch = hh*32 + cc*16 + k2*4 -> swizzled byte:
      const int wbyte = cc * 256 + (k2 >> 1) * 128 + hh * 16 + (k2 & 1) * 8;
      *(uint2*)(LTb + wbyte) = make_uint2(pack2bf(lv0, lv1), pack2bf(lv2, lv3));
    }
  }
  __syncthreads();

  // ---- D-write (chunk-swizzled) into E's dead space ----
#pragma unroll
  for (int ip = 0; ip < 2; ++ip) {
    const float4 bd = *(const float4*)(dec_b + wv * 32 + ip * 16 + quad * 4);
    // ch c0 = wv*32 + ip*16 + quad*4 -> swizzled byte:
    const int dbyte = (2 * ip + (quad >> 1)) * 128 + wv * 16 + (quad & 1) * 8;
#pragma unroll
    for (int j = 0; j < 2; ++j) {
      const int col = j * 16 + fm;
      const unsigned int w0 = pack2bf(acc[4 + ip][j][0] + bd.x, acc[4 + ip][j][1] + bd.y);
      const unsigned int w1 = pack2bf(acc[4 + ip][j][2] + bd.z, acc[4 + ip][j][3] + bd.w);
      *(uint2*)(smem + DOFF + col * DSTR + dbyte) = make_uint2(w0, w1);
    }
  }
  // ---- spectral: in-place on LT (swizzled); sin/cos + angle recurrence ----
  {
    unsigned char* LTp = smem + LTOFF + wv * 2112;
#pragma unroll
    for (int ii = 0; ii < 4; ++ii) {
      const int ic = ii * 64 + lane;  // channel i in [0,256)
      const int swzb = ltswz(ic);
      const float* wrp = weights + ic * 24;
      float wr_[24];
#pragma unroll
      for (int q2 = 0; q2 < 6; ++q2) {
        const float4 wq = *(const float4*)(wrp + q2 * 4);
        wr_[q2 * 4 + 0] = wq.x; wr_[q2 * 4 + 1] = wq.y;
        wr_[q2 * 4 + 2] = wq.z; wr_[q2 * 4 + 3] = wq.w;
      }
#pragma unroll
      for (int l2 = 0; l2 < 4; ++l2) {
        unsigned short* ps = (unsigned short*)(LTp + l2 * LTSTR + swzb);
        const float val = bf2f(*ps);
        const float th = val * 0.26179938779914946f;  // pi/12
        const float sn = __sinf(th), cs = __cosf(th);
        float av = wr_[12];  // m=0: cos term only
        float sm = sn, cm = cs;
#pragma unroll
        for (int mq = 1; mq <= 11; ++mq) {
          av += wr_[mq] * sm + wr_[12 + mq] * cm;
          if (mq < 11) {
            const float ns = sm * cs + cm * sn;
            cm = cm * cs - sm * sn;
            sm = ns;
          }
        }
        *ps = f2bf(av + val);
      }
    }
  }
  __syncthreads();

  // ---- attention 2 + xp + store: ALL 64 lanes (cc, hh, pp) ----
  {
    const int cc = lane >> 5;         // which 16-channel half
    const int hh = (lane >> 2) & 7;
    const int pp = lane & 3;
    const int col = wv * 4 + pp;
    const unsigned char* Db  = smem + DOFF + col * DSTR;
    const unsigned char* LTp = smem + LTOFF + wv * 2112;
    union u4b { uint4 q; unsigned short us[8]; };
    float dq[16];
#pragma unroll
    for (int c8 = 0; c8 < 2; ++c8) {
      // ch = hh*32 + cc*16 + c8*8 -> swizzled chunk byte:
      u4b td; td.q = *(const uint4*)(Db + (2 * cc + c8) * 128 + hh * 16);
#pragma unroll
      for (int e = 0; e < 8; ++e) dq[c8 * 8 + e] = bf2f(td.us[e]);
    }
    float sc2[4];
#pragma unroll
    for (int l2 = 0; l2 < 4; ++l2) {
      float sa = 0.f;
#pragma unroll
      for (int c8 = 0; c8 < 2; ++c8) {
        u4b tl; tl.q = *(const uint4*)(LTp + l2 * LTSTR + (2 * cc + c8) * 128 + hh * 16);
#pragma unroll
        for (int e = 0; e < 8; ++e) sa += dq[c8 * 8 + e] * bf2f(tl.us[e]);
      }
      sc2[l2] = sa + __shfl_xor(sa, 32);   // full 32-chan dot via pair exchange
    }
    const float mx2 = fmaxf(fmaxf(sc2[0], sc2[1]), fmaxf(sc2[2], sc2[3]));
    float ex[4];
#pragma unroll
    for (int l2 = 0; l2 < 4; ++l2) ex[l2] = __expf(sc2[l2] - mx2);
    const float inv2 = 1.f / (ex[0] + ex[1] + ex[2] + ex[3]);
    float aw[4];
#pragma unroll
    for (int l2 = 0; l2 < 4; ++l2) aw[l2] = ex[l2] * inv2;

    const int hpf = chnk * 8 + wv;          // Hp index
    const int hg  = h0 + wv * 4 + pp;       // h index
    float* ob = out + bb * 1048576 + pp * 262144 + hpf * 256 + hh * 32 + cc * 16;
    const float* xc = x + bb * 1048576 + (hh * 32 + cc * 16) * 4096 + hg;
#pragma unroll
    for (int c8 = 0; c8 < 2; ++c8) {
      float ov[8];
#pragma unroll
      for (int e = 0; e < 8; ++e) ov[e] = 0.f;
#pragma unroll
      for (int l2 = 0; l2 < 4; ++l2) {
        u4b tl; tl.q = *(const uint4*)(LTp + l2 * LTSTR + (2 * cc + c8) * 128 + hh * 16);
#pragma unroll
        for (int e = 0; e < 8; ++e) ov[e] += aw[l2] * bf2f(tl.us[e]);
      }
#pragma unroll
      for (int e = 0; e < 8; ++e) ov[e] += xc[(c8 * 8 + e) * 4096];
      *(float4*)(ob + c8 * 8)     = make_float4(ov[0], ov[1], ov[2], ov[3]);
      *(float4*)(ob + c8 * 8 + 4) = make_float4(ov[4], ov[5], ov[6], ov[7]);
    }
  }
}

extern "C" void kernel_launch(void* const* d_in, const int* in_sizes, int n_in,
                              void* d_out, int out_size, void* d_ws, size_t ws_size,
                              hipStream_t stream) {
  const float* x       = (const float*)d_in[0];
  const float* weights = (const float*)d_in[1];
  const float* latent  = (const float*)d_in[2];
  const float* enc_w   = (const float*)d_in[3];
  const float* enc_b   = (const float*)d_in[4];
  const float* dec_w   = (const float*)d_in[5];
  const float* dec_b   = (const float*)d_in[6];
  unsigned short* Wb   = (unsigned short*)d_ws;  // 768*256 bf16 = 384 KB (frag order)
  float* outp          = (float*)d_out;

  wconv_kernel<<<96, 256, 0, stream>>>(enc_w, dec_w, Wb);
  nsb_kernel<<<4096, 512, 0, stream>>>(x, weights, latent, enc_b, dec_b, Wb, outp);
}